// Round 6
// baseline (273.071 us; speedup 1.0000x reference)
//
#include <hip/hip_runtime.h>

// ---------------------------------------------------------------------------
// R_SCNN: two width-direction SCNN scans fused into one 127-step recurrence,
// executed with MFMA, then 4x bilinear upsample + global BN + sigmoid.
//
//   y_w = c_w + relu(M y_{w-1}),  z_w = y_w + relu(M z_{w-1}),  z_0 = y_0 = c_0
//   s[b,h,p] = dot(v, z_{127-p});  out = sigmoid(BN(upsample4(s)))
//
// Round-10: stagger v2. Five rounds of evidence say the step (~2100cy) is
// serial-dependency-latency bound: lockstep waves all stall together on the
// ds_read round trip, MFMA tail, dependent epilogue, write-ack, barrier.
// Fix: each block runs TWO independent (b,h) recurrences in antiphase
// (waves 0-3 = A, waves 4-7 = B; one of each per SIMD). While A does
// read+MFMA, B does epilogue+writes+prefetch. R3 tried this and died from
// (a) launch_bounds(512,2)'s 128-VGPR cap -> 8MB scratch spill, and
// (b) uncoalesced per-lane conv_w gather -> 21MB FETCH. Fixed here:
// launch_bounds(512,1) (256-reg budget, ~248 used), k_extract kept, single
// 8-deep MFMA chain per tile (acc 16 regs), z-history + post-loop dot.
// ---------------------------------------------------------------------------

typedef _Float16 f16x8 __attribute__((ext_vector_type(8)));
typedef _Float16 f16x4 __attribute__((ext_vector_type(4)));
typedef float    f32x4 __attribute__((ext_vector_type(4)));

// Raw workgroup barrier: drain LDS ops only; global (vmcnt) loads stay in
// flight across it.
static __device__ __forceinline__ void sync_lds() {
  asm volatile("s_waitcnt lgkmcnt(0)" ::: "memory");
  __builtin_amdgcn_s_barrier();
  asm volatile("" ::: "memory");
}

// quad_perm(0,0,2,2): lane 2k+1 receives lane 2k's value (VALU-speed, no LDS)
static __device__ __forceinline__ float dpp_even(float v) {
  int t = __builtin_bit_cast(int, v);
  t = __builtin_amdgcn_update_dpp(t, t, 0xA0, 0xF, 0xF, false);
  return __builtin_bit_cast(float, t);
}

// ---- kernel 0: extract center tap of conv_w -> dense f16 [o][c], coalesced -
extern "C" __global__ void k_extract(const float* __restrict__ convw,
                                     _Float16* __restrict__ Md) {
  int q = blockIdx.x * 256 + threadIdx.x;   // 147456 float4s = 589824 floats
  float4 v = ((const float4*)convw)[q];
  float vv[4] = {v.x, v.y, v.z, v.w};
  int f = q * 4;
#pragma unroll
  for (int e = 0; e < 4; ++e) {
    int flat = f + e;                       // flat = idx*9 + 4  <=>  center tap
    if (flat % 9 == 4) Md[flat / 9] = (_Float16)vv[e];
  }
}

// ---- kernel 1: fused double scan via MFMA, 2 antiphase recurrences --------
struct GSM {
  _Float16 cy[256];        // y carry (f16), single buffer (barrier-separated)
  _Float16 pad0[32];       // 64B: z rows shifted 16 banks vs cy
  _Float16 zh[128 * 256];  // z history; row w = z_w (also the z carry)
};
struct SM { GSM g[2]; };   // 2 x 66112 B = 129.2 KB

extern "C" __global__ void __launch_bounds__(512, 1)
k_scan(const float* __restrict__ p2, const _Float16* __restrict__ Md,
       const float* __restrict__ conv1, float* __restrict__ sout,
       float* __restrict__ stats) {
  __shared__ SM sm;
  const int tid  = threadIdx.x;
  const int l    = tid & 63;
  const int wv   = tid >> 6;        // wave 0..7
  const int g    = wv >> 2;         // group: waves 0-3 = A, 4-7 = B
  const int r    = wv & 3;          // wave-in-group 0..3
  const bool gA  = (g == 0);
  const int col  = l & 15;          // MFMA n / A-row-within-tile index
  const int quad = l >> 4;          // MFMA k-group / C-row-group index
  const int gh   = blockIdx.x * 2 + g;   // this group's (b,h)
  const int b    = gh >> 6;
  const int h    = gh & 63;

  if (blockIdx.x == 0 && tid == 0) { stats[0] = 0.f; stats[1] = 0.f; }

  GSM& S = sm.g[g];
  const bool isY   = (col == 0);    // lanes holding C column 0 (y results)
  const bool isZ   = (col == 1);    // lanes holding C column 1 (z results)
  const bool zlane = (l & 1);       // odd cols read the z stream as B

  // C/D rows owned by this lane: tiles 4r..4r+3, rows mrow[t]..mrow[t]+3
  int mrow[4];
#pragma unroll
  for (int t = 0; t < 4; ++t) mrow[t] = (r * 4 + t) * 16 + quad * 4;

  // A-fragments (resident, ideally AGPR): A[m=(4r+t)*16+col][k=ch*32+quad*8+j]
  f16x8 A[4][8];
#pragma unroll
  for (int t = 0; t < 4; ++t)
#pragma unroll
    for (int ch = 0; ch < 8; ++ch)
      A[t][ch] = *(const f16x8*)(Md + ((r*4+t)*16 + col) * 256 + ch*32 + quad*8);

  // p2_r[b][c][h][w]: channel c at pbase + c*8192 + w
  const float* pbase = p2 + (size_t)b * 2097152 + (size_t)h * 128;

  // init: w=0 state (z_0 = y_0 = c_0) into cy and zh row 0
  if (isY) {
#pragma unroll
    for (int t = 0; t < 4; ++t) {
      f16x4 p;
#pragma unroll
      for (int i = 0; i < 4; ++i)
        p[i] = (_Float16)pbase[(size_t)(mrow[t] + i) * 8192];
      *(f16x4*)(S.cy + mrow[t]) = p;
      *(f16x4*)(S.zh + mrow[t]) = p;
    }
  }

  // depth-2 c_w register pipeline (isY lanes): cc = c for odd steps, cn for
  // even steps; each reloads its own set for w+2 across the raw barrier.
  float cc[4][4], cn[4][4];
  if (isY) {
#pragma unroll
    for (int t = 0; t < 4; ++t)
#pragma unroll
      for (int i = 0; i < 4; ++i) {
        cc[t][i] = pbase[(size_t)(mrow[t] + i) * 8192 + 1];
        cn[t][i] = pbase[(size_t)(mrow[t] + i) * 8192 + 2];
      }
  }
  sync_lds();

  // B-fragment sources: even cols read y carry, odd cols read z history.
  const _Float16* pY  = S.cy + quad * 8;       // fixed (single buffer)
  const _Float16* zrd = S.zh + quad * 8;       // row w-1; +256 after each RM
  _Float16*       zwr = S.zh + 256;            // row w;   +256 after each EW

  f32x4 acc[4];   // MFMA accumulators, live across the half-step barrier

  // RM: read carry, run 4 independent 8-deep MFMA chains
#define RM()                                                                   \
  do {                                                                         \
    const _Float16* bs = zlane ? zrd : pY;                                     \
    f16x8 B[8];                                                                \
    _Pragma("unroll")                                                          \
    for (int ch = 0; ch < 8; ++ch)                                             \
      B[ch] = *(const f16x8*)(bs + ch * 32);                                   \
    _Pragma("unroll")                                                          \
    for (int t = 0; t < 4; ++t) acc[t] = (f32x4){0.f, 0.f, 0.f, 0.f};          \
    _Pragma("unroll")                                                          \
    for (int ch = 0; ch < 8; ++ch) {                                           \
      _Pragma("unroll")                                                        \
      for (int t = 0; t < 4; ++t)                                              \
        acc[t] = __builtin_amdgcn_mfma_f32_16x16x32_f16(A[t][ch], B[ch], acc[t],0,0,0); \
    }                                                                          \
    zrd += 256;                                                                \
  } while (0)

  // EW: epilogue (y, DPP handoff, z) + carry/history writes + c prefetch
#define EW(W, C)                                                               \
  do {                                                                         \
    f32x4 yf[4] = {};                                                          \
    if (isY) {                                                                 \
      _Pragma("unroll")                                                        \
      for (int t = 0; t < 4; ++t) {                                            \
        f16x4 yh;                                                              \
        _Pragma("unroll")                                                      \
        for (int i = 0; i < 4; ++i) {                                          \
          yf[t][i] = (C)[t][i] + fmaxf(acc[t][i], 0.f);                        \
          yh[i] = (_Float16)yf[t][i];                                          \
        }                                                                      \
        *(f16x4*)(S.cy + mrow[t]) = yh;                                        \
      }                                                                        \
      if ((W) + 2 < 128) {                                                     \
        _Pragma("unroll")                                                      \
        for (int t = 0; t < 4; ++t)                                            \
          _Pragma("unroll")                                                    \
          for (int i = 0; i < 4; ++i)                                          \
            (C)[t][i] = pbase[(size_t)(mrow[t] + i) * 8192 + (W) + 2];         \
      }                                                                        \
    }                                                                          \
    _Pragma("unroll")                                                          \
    for (int t = 0; t < 4; ++t)                                                \
      _Pragma("unroll")                                                        \
      for (int i = 0; i < 4; ++i)                                              \
        yf[t][i] = dpp_even(yf[t][i]);                                         \
    if (isZ) {                                                                 \
      _Pragma("unroll")                                                        \
      for (int t = 0; t < 4; ++t) {                                            \
        f16x4 zo;                                                              \
        _Pragma("unroll")                                                      \
        for (int i = 0; i < 4; ++i)                                            \
          zo[i] = (_Float16)(yf[t][i] + fmaxf(acc[t][i], 0.f));                \
        *(f16x4*)(zwr + mrow[t]) = zo;                                         \
      }                                                                        \
    }                                                                          \
    zwr += 256;                                                                \
  } while (0)

  // Antiphase schedule: A leads by half a step; 2 barriers per step. Per
  // phase each SIMD has one RM wave (DS+MFMA) and one EW wave (VALU+writes).
#pragma unroll 1
  for (int w = 1; w < 127; w += 2) {
    if (gA) RM(); else { if (w > 1) EW(w - 1, cn); }   // w-1 even
    sync_lds();
    if (gA) EW(w, cc); else RM();                      // w odd
    sync_lds();
    if (gA) RM(); else EW(w, cc);
    sync_lds();
    if (gA) EW(w + 1, cn); else RM();                  // w+1 even
    sync_lds();
  }
  // tail: w = 127 (odd); B still owes EW(126), then both finish 127
  if (gA) RM(); else EW(126, cn);
  sync_lds();
  if (gA) EW(127, cc); else RM();
  sync_lds();
  if (!gA) EW(127, cc);
  sync_lds();
#undef RM
#undef EW

  // s[b,h,127-w] = dot(v, z_w): 2 threads per (group, w), 128 channels each
  {
    const int rg   = tid >> 8;          // group
    const int w    = (tid >> 1) & 127;
    const int part = tid & 1;
    const _Float16* zr = sm.g[rg].zh + w * 256 + part * 128;
    const float*    vr = conv1 + part * 128;
    float s = 0.f;
#pragma unroll
    for (int j = 0; j < 16; ++j) {
      f16x8 zv = *(const f16x8*)(zr + j * 8);
      float4 v0 = *(const float4*)(vr + j * 8);
      float4 v1 = *(const float4*)(vr + j * 8 + 4);
      s += v0.x * (float)zv[0] + v0.y * (float)zv[1]
         + v0.z * (float)zv[2] + v0.w * (float)zv[3]
         + v1.x * (float)zv[4] + v1.y * (float)zv[5]
         + v1.z * (float)zv[6] + v1.w * (float)zv[7];
    }
    s += __shfl_xor(s, 1, 64);
    if (part == 0)
      sout[((blockIdx.x * 2 + rg) << 7) + (127 - w)] = s;
  }
}

// ---- bilinear 4x upsample (align_corners) of s: (2,64,128) -> (2,256,512) --
static __device__ __forceinline__ float bilin(const float* __restrict__ s,
                                              int idx) {
  int bb  = idx >> 17;
  int rem = idx & 131071;
  int ho  = rem >> 9;
  int wo  = rem & 511;
  const float SY = 63.0f / 255.0f, SX = 127.0f / 511.0f;
  float fy = (float)ho * SY;
  int y0 = (int)fy; int y1 = min(y0 + 1, 63); float wy = fy - (float)y0;
  float fx = (float)wo * SX;
  int x0 = (int)fx; int x1 = min(x0 + 1, 127); float wx = fx - (float)x0;
  const float* sb = s + bb * 8192;
  float cA = sb[y0 * 128 + x0] * (1.f - wy) + sb[y1 * 128 + x0] * wy;
  float cB = sb[y0 * 128 + x1] * (1.f - wy) + sb[y1 * 128 + x1] * wy;
  return cA * (1.f - wx) + cB * wx;
}

// ---- kernel 2: global sum / sumsq of upsampled field -----------------------
extern "C" __global__ void k_stats(const float* __restrict__ s,
                                   float* __restrict__ stats) {
  int tid  = threadIdx.x;
  int base = blockIdx.x * 1024 + tid;
  float sum = 0.f, ssq = 0.f;
#pragma unroll
  for (int i = 0; i < 4; ++i) {
    float u = bilin(s, base + i * 256);
    sum += u; ssq += u * u;
  }
#pragma unroll
  for (int off = 32; off > 0; off >>= 1) {
    sum += __shfl_xor(sum, off, 64);
    ssq += __shfl_xor(ssq, off, 64);
  }
  __shared__ float ls[4], lq[4];
  int wv = tid >> 6;
  if ((tid & 63) == 0) { ls[wv] = sum; lq[wv] = ssq; }
  __syncthreads();
  if (tid == 0) {
    atomicAdd(&stats[0], ls[0] + ls[1] + ls[2] + ls[3]);
    atomicAdd(&stats[1], lq[0] + lq[1] + lq[2] + lq[3]);
  }
}

// ---- kernel 3: normalize + sigmoid -----------------------------------------
extern "C" __global__ void k_norm(const float* __restrict__ s,
                                  const float* __restrict__ stats,
                                  const float* __restrict__ gamma,
                                  const float* __restrict__ beta,
                                  float* __restrict__ out) {
  int tid  = threadIdx.x;
  int base = blockIdx.x * 1024 + tid;
  const float invN = 1.f / 262144.f;
  float mean  = stats[0] * invN;
  float var   = stats[1] * invN - mean * mean;
  float scale = rsqrtf(var + 1e-5f) * gamma[0];
  float bias  = beta[0] - mean * scale;
#pragma unroll
  for (int i = 0; i < 4; ++i) {
    int idx = base + i * 256;
    float u = bilin(s, idx);
    float x = u * scale + bias;
    out[idx] = 1.f / (1.f + __expf(-x));
  }
}

// ---------------------------------------------------------------------------
extern "C" void kernel_launch(void* const* d_in, const int* in_sizes, int n_in,
                              void* d_out, int out_size, void* d_ws, size_t ws_size,
                              hipStream_t stream) {
  const float* p2    = (const float*)d_in[0];   // (2,256,64,128)
  const float* convw = (const float*)d_in[1];   // (256,256,1,9)
  const float* conv1 = (const float*)d_in[2];   // (1,256,1,1)
  const float* gamma = (const float*)d_in[3];   // (1,)
  const float* beta  = (const float*)d_in[4];   // (1,)
  float* out = (float*)d_out;                   // (2,1,256,512) fp32

  char* ws = (char*)d_ws;
  float*    s     = (float*)ws;                 // 16384 floats  [0, 64KB)
  float*    stats = (float*)(ws + 65536);       // 2 floats
  _Float16* Md    = (_Float16*)(ws + 65792);    // 65536 f16 (128 KB)

  hipLaunchKernelGGL(k_extract, dim3(576), dim3(256), 0, stream, convw, Md);
  hipLaunchKernelGGL(k_scan,    dim3(64),  dim3(512), 0, stream, p2, Md, conv1, s, stats);
  hipLaunchKernelGGL(k_stats,   dim3(256), dim3(256), 0, stream, s, stats);
  hipLaunchKernelGGL(k_norm,    dim3(256), dim3(256), 0, stream, s, stats, gamma, beta, out);
}

// Round 7
// 220.539 us; speedup vs baseline: 1.2382x; 1.2382x over previous
//
#include <hip/hip_runtime.h>

// ---------------------------------------------------------------------------
// R_SCNN: two width-direction SCNN scans fused into one 127-step recurrence,
// executed with MFMA, ONE barrier per step, then 4x bilinear upsample +
// global BN + sigmoid.
//
//   y_w = c_w + relu(M y_{w-1}),  z_w = y_w + relu(M z_{w-1}),  z_0 = y_0 = c_0
//   s[b,h,p] = dot(v, z_{127-p});  out = sigmoid(BN(upsample4(s)))
//
// Round-11: R1 structure (best: 8 waves x 2 tiles, raw lgkm-only barrier,
// DPP y->z handoff, z-history + post-loop dot) + two safe wins:
//  (1) float4 c-prefetch: c_w rows are contiguous in w, so two ping-pong
//      float4 sets (p/q) cover 4 steps each; 8 dwordx4 issued per 4 steps
//      at block end (~4-step slack) replace 8 scalar loads + addressing
//      inside EVERY step's critical tail. launch_bounds(512,1): grid=128
//      on 256 CUs means 1 block/CU regardless, so the old (512,2) 128-reg
//      cap was pure downside; 256-reg budget removes all spill risk.
//  (2) k_stats + k_norm fused into one kernel (device-scope atomic counter
//      + co-resident spin, 256 blocks x 4 waves), keeping the 4 bilin
//      values in registers across the sync -> one less launch, no upsample
//      recompute.
// Evidence recap: step cost is per-CU DS-instruction drain + fixed barrier
// round (R2/R5/R6 discriminators); stagger designs regress, exchange
// structure is at its local optimum.
// ---------------------------------------------------------------------------

typedef _Float16 f16x8 __attribute__((ext_vector_type(8)));
typedef _Float16 f16x4 __attribute__((ext_vector_type(4)));
typedef float    f32x4 __attribute__((ext_vector_type(4)));

// Raw workgroup barrier: drain LDS ops only; global (vmcnt) loads stay in
// flight across it.
static __device__ __forceinline__ void sync_lds() {
  asm volatile("s_waitcnt lgkmcnt(0)" ::: "memory");
  __builtin_amdgcn_s_barrier();
  asm volatile("" ::: "memory");
}

// quad_perm(0,0,2,2): lane 2k+1 receives lane 2k's value (VALU-speed, no LDS)
static __device__ __forceinline__ float dpp_even(float v) {
  int t = __builtin_bit_cast(int, v);
  t = __builtin_amdgcn_update_dpp(t, t, 0xA0, 0xF, 0xF, false);
  return __builtin_bit_cast(float, t);
}

// ---- kernel 0: extract center tap of conv_w -> dense f16 [o][c], coalesced -
extern "C" __global__ void k_extract(const float* __restrict__ convw,
                                     _Float16* __restrict__ Md) {
  int q = blockIdx.x * 256 + threadIdx.x;   // 147456 float4s = 589824 floats
  float4 v = ((const float4*)convw)[q];
  float vv[4] = {v.x, v.y, v.z, v.w};
  int f = q * 4;
#pragma unroll
  for (int e = 0; e < 4; ++e) {
    int flat = f + e;                       // flat = idx*9 + 4  <=>  center tap
    if (flat % 9 == 4) Md[flat / 9] = (_Float16)vv[e];
  }
}

// ---- kernel 1: fused double scan via MFMA ---------------------------------
struct SM {
  _Float16 cy[2][256];     // y carry (f16), ping-pong            [byte 0)
  _Float16 pad_[32];       // 64B: shifts z rows' banks by 16 vs cy
  _Float16 zh[128 * 256];  // z history; row w = z_w (also z carry) [byte 1088)
};

extern "C" __global__ void __launch_bounds__(512, 1)
k_scan(const float* __restrict__ p2, const _Float16* __restrict__ Md,
       const float* __restrict__ conv1, float* __restrict__ sout,
       float* __restrict__ stats) {
  __shared__ SM sm;
  const int tid  = threadIdx.x;
  const int l    = tid & 63;
  const int r    = tid >> 6;        // wave 0..7
  const int col  = l & 15;          // MFMA n / A-row-within-tile index
  const int quad = l >> 4;          // MFMA k-group / C-row-group index
  const int b    = blockIdx.x >> 6;
  const int h    = blockIdx.x & 63;

  if (blockIdx.x == 0 && tid == 0) {
    stats[0] = 0.f; stats[1] = 0.f; ((int*)stats)[2] = 0;
  }

  const bool isY   = (col == 0);    // lanes holding C column 0 (y results)
  const bool isZ   = (col == 1);    // lanes holding C column 1 (z results)
  const bool zlane = (l & 1);       // odd cols read the z stream as B

  // C/D rows owned by this lane: m0..m0+3 (tile 0), m1..m1+3 (tile 1)
  const int m0 = (r * 2 + 0) * 16 + quad * 4;
  const int m1 = (r * 2 + 1) * 16 + quad * 4;

  // A-fragments (M matrix, AGPR-resident): A[m=t*16+col][k=ch*32+quad*8+j]
  f16x8 A0[8], A1[8];
#pragma unroll
  for (int ch = 0; ch < 8; ++ch) {
    A0[ch] = *(const f16x8*)(Md + ((r*2+0)*16 + col) * 256 + ch*32 + quad*8);
    A1[ch] = *(const f16x8*)(Md + ((r*2+1)*16 + col) * 256 + ch*32 + quad*8);
  }

  // p2_r[b][c][h][w]: channel c at pbase + c*8192 + w
  const float* pbase = p2 + (size_t)b * 2097152 + (size_t)h * 128;

  // float4 c-pipeline (isY lanes): set p covers w-block 4j (j even), set q
  // covers 4j (j odd). Each float4 = c at [row][w0..w0+3]; 16B aligned.
  float4 pA[4], pB[4], qA[4], qB[4];
  if (isY) {
#pragma unroll
    for (int i = 0; i < 4; ++i) {
      pA[i] = *(const float4*)(pbase + (size_t)(m0 + i) * 8192);
      pB[i] = *(const float4*)(pbase + (size_t)(m1 + i) * 8192);
      qA[i] = *(const float4*)(pbase + (size_t)(m0 + i) * 8192 + 4);
      qB[i] = *(const float4*)(pbase + (size_t)(m1 + i) * 8192 + 4);
    }
  }

  // init: w=0 state (z_0 = y_0 = c_0) into cy[0] and zh row 0 (c_0 = pX.x)
  if (isY) {
    f16x4 pa, pb;
#pragma unroll
    for (int i = 0; i < 4; ++i) {
      pa[i] = (_Float16)pA[i].x; pb[i] = (_Float16)pB[i].x;
    }
    *(f16x4*)(sm.cy[0] + m0) = pa; *(f16x4*)(sm.cy[0] + m1) = pb;
    *(f16x4*)(sm.zh    + m0) = pa; *(f16x4*)(sm.zh    + m1) = pb;
  }
  sync_lds();

  // B-fragment sources: even cols read y ping-pong, odd cols read z history.
  const _Float16* pY0 = sm.cy[0] + quad * 8;   // read on odd steps
  const _Float16* pY1 = sm.cy[1] + quad * 8;   // read on even steps
  const _Float16* zrd = sm.zh + quad * 8;      // row w-1; +256/step
  _Float16*       zwr = sm.zh + 256;           // row w;   +256/step

  // STEP: one recurrence step. COMP picks the float4 member (w&3).
#define STEP(PY, WY, CA, CB, COMP)                                             \
  do {                                                                         \
    const _Float16* bsrc = zlane ? zrd : (PY);                                 \
    f16x8 B[8];                                                                \
    _Pragma("unroll")                                                          \
    for (int ch = 0; ch < 8; ++ch)                                             \
      B[ch] = *(const f16x8*)(bsrc + ch * 32);                                 \
    f32x4 a00 = {0.f,0.f,0.f,0.f}, a01 = {0.f,0.f,0.f,0.f};                    \
    f32x4 a10 = {0.f,0.f,0.f,0.f}, a11 = {0.f,0.f,0.f,0.f};                    \
    _Pragma("unroll")                                                          \
    for (int ch = 0; ch < 4; ++ch) {                                           \
      a00 = __builtin_amdgcn_mfma_f32_16x16x32_f16(A0[ch],   B[ch],   a00,0,0,0);\
      a10 = __builtin_amdgcn_mfma_f32_16x16x32_f16(A1[ch],   B[ch],   a10,0,0,0);\
      a01 = __builtin_amdgcn_mfma_f32_16x16x32_f16(A0[ch+4], B[ch+4], a01,0,0,0);\
      a11 = __builtin_amdgcn_mfma_f32_16x16x32_f16(A1[ch+4], B[ch+4], a11,0,0,0);\
    }                                                                          \
    f32x4 acc0 = a00 + a01, acc1 = a10 + a11;                                  \
    f32x4 yf0 = {}, yf1 = {};                                                  \
    if (isY) {                                                                 \
      f16x4 yh0, yh1;                                                          \
      _Pragma("unroll")                                                        \
      for (int i = 0; i < 4; ++i) {                                            \
        yf0[i] = (CA)[i].COMP + fmaxf(acc0[i], 0.f);                           \
        yf1[i] = (CB)[i].COMP + fmaxf(acc1[i], 0.f);                           \
        yh0[i] = (_Float16)yf0[i]; yh1[i] = (_Float16)yf1[i];                  \
      }                                                                        \
      *(f16x4*)((WY) + m0) = yh0;                                              \
      *(f16x4*)((WY) + m1) = yh1;                                              \
    }                                                                          \
    _Pragma("unroll")                                                          \
    for (int i = 0; i < 4; ++i) {                                              \
      yf0[i] = dpp_even(yf0[i]);                                               \
      yf1[i] = dpp_even(yf1[i]);                                               \
    }                                                                          \
    if (isZ) {                                                                 \
      f16x4 zh0, zh1;                                                          \
      _Pragma("unroll")                                                        \
      for (int i = 0; i < 4; ++i) {                                            \
        zh0[i] = (_Float16)(yf0[i] + fmaxf(acc0[i], 0.f));                     \
        zh1[i] = (_Float16)(yf1[i] + fmaxf(acc1[i], 0.f));                     \
      }                                                                        \
      *(f16x4*)(zwr + m0) = zh0;                                               \
      *(f16x4*)(zwr + m1) = zh1;                                               \
    }                                                                          \
    zrd += 256; zwr += 256;                                                    \
    sync_lds();                                                                \
  } while (0)

  // REFILL: reload a float4 set for w-block starting at W0 (clamped so the
  // float4 stays in-bounds; clamped dups are never consumed).
#define REFILL(SA, SB, W0)                                                     \
  do {                                                                         \
    if (isY) {                                                                 \
      int wt = (W0) <= 124 ? (W0) : 124;                                       \
      _Pragma("unroll")                                                        \
      for (int i = 0; i < 4; ++i) {                                            \
        SA[i] = *(const float4*)(pbase + (size_t)(m0 + i) * 8192 + wt);        \
        SB[i] = *(const float4*)(pbase + (size_t)(m1 + i) * 8192 + wt);        \
      }                                                                        \
    }                                                                          \
  } while (0)

  // prologue steps w = 1,2,3 (set p, comps 1..3), then refill p for w=8..11
  STEP(pY0, sm.cy[1], pA, pB, y);
  STEP(pY1, sm.cy[0], pA, pB, z);
  STEP(pY0, sm.cy[1], pA, pB, w);
  REFILL(pA, pB, 8);

  // main: 15 iterations x 8 steps cover w = 4..123
  int w0 = 4;
#pragma unroll 1
  for (int it = 0; it < 15; ++it) {
    STEP(pY1, sm.cy[0], qA, qB, x);   // w0+0 (even)
    STEP(pY0, sm.cy[1], qA, qB, y);   // w0+1
    STEP(pY1, sm.cy[0], qA, qB, z);   // w0+2
    STEP(pY0, sm.cy[1], qA, qB, w);   // w0+3
    REFILL(qA, qB, w0 + 8);
    STEP(pY1, sm.cy[0], pA, pB, x);   // w0+4
    STEP(pY0, sm.cy[1], pA, pB, y);   // w0+5
    STEP(pY1, sm.cy[0], pA, pB, z);   // w0+6
    STEP(pY0, sm.cy[1], pA, pB, w);   // w0+7
    REFILL(pA, pB, w0 + 12);
    w0 += 8;
  }

  // tail: w = 124..127 (set q)
  STEP(pY1, sm.cy[0], qA, qB, x);
  STEP(pY0, sm.cy[1], qA, qB, y);
  STEP(pY1, sm.cy[0], qA, qB, z);
  STEP(pY0, sm.cy[1], qA, qB, w);
#undef STEP
#undef REFILL

  // s[b,h,127-w] = dot(v, z_w): 4 threads per w, 64 channels each
  {
    const int w    = tid >> 2;
    const int part = tid & 3;
    const _Float16* zr = sm.zh + w * 256 + part * 64;
    const float*    vr = conv1 + part * 64;
    float s = 0.f;
#pragma unroll
    for (int j = 0; j < 8; ++j) {
      f16x8 zv = *(const f16x8*)(zr + j * 8);
      float4 v0 = *(const float4*)(vr + j * 8);
      float4 v1 = *(const float4*)(vr + j * 8 + 4);
      s += v0.x * (float)zv[0] + v0.y * (float)zv[1]
         + v0.z * (float)zv[2] + v0.w * (float)zv[3]
         + v1.x * (float)zv[4] + v1.y * (float)zv[5]
         + v1.z * (float)zv[6] + v1.w * (float)zv[7];
    }
    s += __shfl_xor(s, 1, 64);
    s += __shfl_xor(s, 2, 64);
    if (part == 0) sout[(blockIdx.x << 7) + (127 - w)] = s;
  }
}

// ---- bilinear 4x upsample (align_corners) of s: (2,64,128) -> (2,256,512) --
static __device__ __forceinline__ float bilin(const float* __restrict__ s,
                                              int idx) {
  int bb  = idx >> 17;
  int rem = idx & 131071;
  int ho  = rem >> 9;
  int wo  = rem & 511;
  const float SY = 63.0f / 255.0f, SX = 127.0f / 511.0f;
  float fy = (float)ho * SY;
  int y0 = (int)fy; int y1 = min(y0 + 1, 63); float wy = fy - (float)y0;
  float fx = (float)wo * SX;
  int x0 = (int)fx; int x1 = min(x0 + 1, 127); float wx = fx - (float)x0;
  const float* sb = s + bb * 8192;
  float cA = sb[y0 * 128 + x0] * (1.f - wy) + sb[y1 * 128 + x0] * wy;
  float cB = sb[y0 * 128 + x1] * (1.f - wy) + sb[y1 * 128 + x1] * wy;
  return cA * (1.f - wx) + cB * wx;
}

// ---- kernel 2: fused stats + normalize + sigmoid --------------------------
// 256 blocks x 256 threads (4 waves) -- trivially co-resident on 256 CUs, so
// a device-scope counter + spin replaces the k_stats/k_norm launch pair. The
// 4 bilin values stay live in registers across the sync (no recompute).
extern "C" __global__ void k_statsnorm(const float* __restrict__ s,
                                       float* __restrict__ stats,
                                       const float* __restrict__ gamma,
                                       const float* __restrict__ beta,
                                       float* __restrict__ out) {
  int tid  = threadIdx.x;
  int base = blockIdx.x * 1024 + tid;
  float u[4];
  float sum = 0.f, ssq = 0.f;
#pragma unroll
  for (int i = 0; i < 4; ++i) {
    u[i] = bilin(s, base + i * 256);
    sum += u[i]; ssq += u[i] * u[i];
  }
#pragma unroll
  for (int off = 32; off > 0; off >>= 1) {
    sum += __shfl_xor(sum, off, 64);
    ssq += __shfl_xor(ssq, off, 64);
  }
  __shared__ float ls[4], lq[4];
  int wv = tid >> 6;
  if ((tid & 63) == 0) { ls[wv] = sum; lq[wv] = ssq; }
  __syncthreads();
  int* cnt = (int*)stats + 2;
  if (tid == 0) {
    atomicAdd(&stats[0], ls[0] + ls[1] + ls[2] + ls[3]);
    atomicAdd(&stats[1], lq[0] + lq[1] + lq[2] + lq[3]);
    __threadfence();
    atomicAdd(cnt, 1);
  }
  // spin until all 256 blocks contributed (volatile -> L1-bypass each poll)
  volatile int* vc = cnt;
  while (*vc < 256) { __builtin_amdgcn_s_sleep(8); }
  __threadfence();

  const float invN = 1.f / 262144.f;
  float mean  = stats[0] * invN;
  float var   = stats[1] * invN - mean * mean;
  float scale = rsqrtf(var + 1e-5f) * gamma[0];
  float bias  = beta[0] - mean * scale;
#pragma unroll
  for (int i = 0; i < 4; ++i) {
    float x = u[i] * scale + bias;
    out[base + i * 256] = 1.f / (1.f + __expf(-x));
  }
}

// ---------------------------------------------------------------------------
extern "C" void kernel_launch(void* const* d_in, const int* in_sizes, int n_in,
                              void* d_out, int out_size, void* d_ws, size_t ws_size,
                              hipStream_t stream) {
  const float* p2    = (const float*)d_in[0];   // (2,256,64,128)
  const float* convw = (const float*)d_in[1];   // (256,256,1,9)
  const float* conv1 = (const float*)d_in[2];   // (1,256,1,1)
  const float* gamma = (const float*)d_in[3];   // (1,)
  const float* beta  = (const float*)d_in[4];   // (1,)
  float* out = (float*)d_out;                   // (2,1,256,512) fp32

  char* ws = (char*)d_ws;
  float*    s     = (float*)ws;                 // 16384 floats  [0, 64KB)
  float*    stats = (float*)(ws + 65536);       // stats[0..1] + int counter
  _Float16* Md    = (_Float16*)(ws + 65792);    // 65536 f16 (128 KB)

  hipLaunchKernelGGL(k_extract,   dim3(576), dim3(256), 0, stream, convw, Md);
  hipLaunchKernelGGL(k_scan,      dim3(128), dim3(512), 0, stream, p2, Md, conv1, s, stats);
  hipLaunchKernelGGL(k_statsnorm, dim3(256), dim3(256), 0, stream, s, stats, gamma, beta, out);
}

// Round 8
// 176.550 us; speedup vs baseline: 1.5467x; 1.2492x over previous
//
#include <hip/hip_runtime.h>

// ---------------------------------------------------------------------------
// R_SCNN: two width-direction SCNN scans fused into one 127-step recurrence,
// executed with MFMA, ONE barrier per step, then 4x bilinear upsample +
// global BN + sigmoid.
//
//   y_w = c_w + relu(M y_{w-1}),  z_w = y_w + relu(M z_{w-1}),  z_0 = y_0 = c_0
//   s[b,h,p] = dot(v, z_{127-p});  out = sigmoid(BN(upsample4(s)))
//
// Round-12 (consolidation): keep R7's k_scan (float4 c-prefetch ping-pong,
// launch_bounds(512,1), raw lgkm-only barrier, DPP y->z handoff, z-history +
// post-loop dot; measured 103.5us, no spills). REVERT the fused
// k_statsnorm: the hand-rolled counter+spin grid sync cost ~100us (65536
// threads polling one cacheline across 8 non-coherent XCD L2s = HBM-class
// round trip per poll + straggler skew). Separate k_stats/k_norm epilogue
// restored (R1 version, ~20us total).
// Evidence ledger for the scan's ~800ns/step floor: fewer waves = worse
// (R2), less DS data = null (R5), vmcnt drain fix = -100cy (R1), stagger
// x2 = much worse (R3/R6), prefetch streamlining = -60cy (R7). The floor is
// the write->barrier->read->MFMA round trip itself; all pipes <25% busy.
// ---------------------------------------------------------------------------

typedef _Float16 f16x8 __attribute__((ext_vector_type(8)));
typedef _Float16 f16x4 __attribute__((ext_vector_type(4)));
typedef float    f32x4 __attribute__((ext_vector_type(4)));

// Raw workgroup barrier: drain LDS ops only; global (vmcnt) loads stay in
// flight across it.
static __device__ __forceinline__ void sync_lds() {
  asm volatile("s_waitcnt lgkmcnt(0)" ::: "memory");
  __builtin_amdgcn_s_barrier();
  asm volatile("" ::: "memory");
}

// quad_perm(0,0,2,2): lane 2k+1 receives lane 2k's value (VALU-speed, no LDS)
static __device__ __forceinline__ float dpp_even(float v) {
  int t = __builtin_bit_cast(int, v);
  t = __builtin_amdgcn_update_dpp(t, t, 0xA0, 0xF, 0xF, false);
  return __builtin_bit_cast(float, t);
}

// ---- kernel 0: extract center tap of conv_w -> dense f16 [o][c], coalesced -
extern "C" __global__ void k_extract(const float* __restrict__ convw,
                                     _Float16* __restrict__ Md) {
  int q = blockIdx.x * 256 + threadIdx.x;   // 147456 float4s = 589824 floats
  float4 v = ((const float4*)convw)[q];
  float vv[4] = {v.x, v.y, v.z, v.w};
  int f = q * 4;
#pragma unroll
  for (int e = 0; e < 4; ++e) {
    int flat = f + e;                       // flat = idx*9 + 4  <=>  center tap
    if (flat % 9 == 4) Md[flat / 9] = (_Float16)vv[e];
  }
}

// ---- kernel 1: fused double scan via MFMA ---------------------------------
struct SM {
  _Float16 cy[2][256];     // y carry (f16), ping-pong            [byte 0)
  _Float16 pad_[32];       // 64B: shifts z rows' banks by 16 vs cy
  _Float16 zh[128 * 256];  // z history; row w = z_w (also z carry) [byte 1088)
};

extern "C" __global__ void __launch_bounds__(512, 1)
k_scan(const float* __restrict__ p2, const _Float16* __restrict__ Md,
       const float* __restrict__ conv1, float* __restrict__ sout,
       float* __restrict__ stats) {
  __shared__ SM sm;
  const int tid  = threadIdx.x;
  const int l    = tid & 63;
  const int r    = tid >> 6;        // wave 0..7
  const int col  = l & 15;          // MFMA n / A-row-within-tile index
  const int quad = l >> 4;          // MFMA k-group / C-row-group index
  const int b    = blockIdx.x >> 6;
  const int h    = blockIdx.x & 63;

  if (blockIdx.x == 0 && tid == 0) { stats[0] = 0.f; stats[1] = 0.f; }

  const bool isY   = (col == 0);    // lanes holding C column 0 (y results)
  const bool isZ   = (col == 1);    // lanes holding C column 1 (z results)
  const bool zlane = (l & 1);       // odd cols read the z stream as B

  // C/D rows owned by this lane: m0..m0+3 (tile 0), m1..m1+3 (tile 1)
  const int m0 = (r * 2 + 0) * 16 + quad * 4;
  const int m1 = (r * 2 + 1) * 16 + quad * 4;

  // A-fragments (M matrix, AGPR-resident): A[m=t*16+col][k=ch*32+quad*8+j]
  f16x8 A0[8], A1[8];
#pragma unroll
  for (int ch = 0; ch < 8; ++ch) {
    A0[ch] = *(const f16x8*)(Md + ((r*2+0)*16 + col) * 256 + ch*32 + quad*8);
    A1[ch] = *(const f16x8*)(Md + ((r*2+1)*16 + col) * 256 + ch*32 + quad*8);
  }

  // p2_r[b][c][h][w]: channel c at pbase + c*8192 + w
  const float* pbase = p2 + (size_t)b * 2097152 + (size_t)h * 128;

  // float4 c-pipeline (isY lanes): set p covers w-block 4j (j even), set q
  // covers 4j (j odd). Each float4 = c at [row][w0..w0+3]; 16B aligned.
  float4 pA[4], pB[4], qA[4], qB[4];
  if (isY) {
#pragma unroll
    for (int i = 0; i < 4; ++i) {
      pA[i] = *(const float4*)(pbase + (size_t)(m0 + i) * 8192);
      pB[i] = *(const float4*)(pbase + (size_t)(m1 + i) * 8192);
      qA[i] = *(const float4*)(pbase + (size_t)(m0 + i) * 8192 + 4);
      qB[i] = *(const float4*)(pbase + (size_t)(m1 + i) * 8192 + 4);
    }
  }

  // init: w=0 state (z_0 = y_0 = c_0) into cy[0] and zh row 0 (c_0 = pX.x)
  if (isY) {
    f16x4 pa, pb;
#pragma unroll
    for (int i = 0; i < 4; ++i) {
      pa[i] = (_Float16)pA[i].x; pb[i] = (_Float16)pB[i].x;
    }
    *(f16x4*)(sm.cy[0] + m0) = pa; *(f16x4*)(sm.cy[0] + m1) = pb;
    *(f16x4*)(sm.zh    + m0) = pa; *(f16x4*)(sm.zh    + m1) = pb;
  }
  sync_lds();

  // B-fragment sources: even cols read y ping-pong, odd cols read z history.
  const _Float16* pY0 = sm.cy[0] + quad * 8;   // read on odd steps
  const _Float16* pY1 = sm.cy[1] + quad * 8;   // read on even steps
  const _Float16* zrd = sm.zh + quad * 8;      // row w-1; +256/step
  _Float16*       zwr = sm.zh + 256;           // row w;   +256/step

  // STEP: one recurrence step. COMP picks the float4 member (w&3).
#define STEP(PY, WY, CA, CB, COMP)                                             \
  do {                                                                         \
    const _Float16* bsrc = zlane ? zrd : (PY);                                 \
    f16x8 B[8];                                                                \
    _Pragma("unroll")                                                          \
    for (int ch = 0; ch < 8; ++ch)                                             \
      B[ch] = *(const f16x8*)(bsrc + ch * 32);                                 \
    f32x4 a00 = {0.f,0.f,0.f,0.f}, a01 = {0.f,0.f,0.f,0.f};                    \
    f32x4 a10 = {0.f,0.f,0.f,0.f}, a11 = {0.f,0.f,0.f,0.f};                    \
    _Pragma("unroll")                                                          \
    for (int ch = 0; ch < 4; ++ch) {                                           \
      a00 = __builtin_amdgcn_mfma_f32_16x16x32_f16(A0[ch],   B[ch],   a00,0,0,0);\
      a10 = __builtin_amdgcn_mfma_f32_16x16x32_f16(A1[ch],   B[ch],   a10,0,0,0);\
      a01 = __builtin_amdgcn_mfma_f32_16x16x32_f16(A0[ch+4], B[ch+4], a01,0,0,0);\
      a11 = __builtin_amdgcn_mfma_f32_16x16x32_f16(A1[ch+4], B[ch+4], a11,0,0,0);\
    }                                                                          \
    f32x4 acc0 = a00 + a01, acc1 = a10 + a11;                                  \
    f32x4 yf0 = {}, yf1 = {};                                                  \
    if (isY) {                                                                 \
      f16x4 yh0, yh1;                                                          \
      _Pragma("unroll")                                                        \
      for (int i = 0; i < 4; ++i) {                                            \
        yf0[i] = (CA)[i].COMP + fmaxf(acc0[i], 0.f);                           \
        yf1[i] = (CB)[i].COMP + fmaxf(acc1[i], 0.f);                           \
        yh0[i] = (_Float16)yf0[i]; yh1[i] = (_Float16)yf1[i];                  \
      }                                                                        \
      *(f16x4*)((WY) + m0) = yh0;                                              \
      *(f16x4*)((WY) + m1) = yh1;                                              \
    }                                                                          \
    _Pragma("unroll")                                                          \
    for (int i = 0; i < 4; ++i) {                                              \
      yf0[i] = dpp_even(yf0[i]);                                               \
      yf1[i] = dpp_even(yf1[i]);                                               \
    }                                                                          \
    if (isZ) {                                                                 \
      f16x4 zh0, zh1;                                                          \
      _Pragma("unroll")                                                        \
      for (int i = 0; i < 4; ++i) {                                            \
        zh0[i] = (_Float16)(yf0[i] + fmaxf(acc0[i], 0.f));                     \
        zh1[i] = (_Float16)(yf1[i] + fmaxf(acc1[i], 0.f));                     \
      }                                                                        \
      *(f16x4*)(zwr + m0) = zh0;                                               \
      *(f16x4*)(zwr + m1) = zh1;                                               \
    }                                                                          \
    zrd += 256; zwr += 256;                                                    \
    sync_lds();                                                                \
  } while (0)

  // REFILL: reload a float4 set for w-block starting at W0 (clamped so the
  // float4 stays in-bounds; clamped dups are never consumed).
#define REFILL(SA, SB, W0)                                                     \
  do {                                                                         \
    if (isY) {                                                                 \
      int wt = (W0) <= 124 ? (W0) : 124;                                       \
      _Pragma("unroll")                                                        \
      for (int i = 0; i < 4; ++i) {                                            \
        SA[i] = *(const float4*)(pbase + (size_t)(m0 + i) * 8192 + wt);        \
        SB[i] = *(const float4*)(pbase + (size_t)(m1 + i) * 8192 + wt);        \
      }                                                                        \
    }                                                                          \
  } while (0)

  // prologue steps w = 1,2,3 (set p, comps 1..3), then refill p for w=8..11
  STEP(pY0, sm.cy[1], pA, pB, y);
  STEP(pY1, sm.cy[0], pA, pB, z);
  STEP(pY0, sm.cy[1], pA, pB, w);
  REFILL(pA, pB, 8);

  // main: 15 iterations x 8 steps cover w = 4..123
  int w0 = 4;
#pragma unroll 1
  for (int it = 0; it < 15; ++it) {
    STEP(pY1, sm.cy[0], qA, qB, x);   // w0+0 (even)
    STEP(pY0, sm.cy[1], qA, qB, y);   // w0+1
    STEP(pY1, sm.cy[0], qA, qB, z);   // w0+2
    STEP(pY0, sm.cy[1], qA, qB, w);   // w0+3
    REFILL(qA, qB, w0 + 8);
    STEP(pY1, sm.cy[0], pA, pB, x);   // w0+4
    STEP(pY0, sm.cy[1], pA, pB, y);   // w0+5
    STEP(pY1, sm.cy[0], pA, pB, z);   // w0+6
    STEP(pY0, sm.cy[1], pA, pB, w);   // w0+7
    REFILL(pA, pB, w0 + 12);
    w0 += 8;
  }

  // tail: w = 124..127 (set q)
  STEP(pY1, sm.cy[0], qA, qB, x);
  STEP(pY0, sm.cy[1], qA, qB, y);
  STEP(pY1, sm.cy[0], qA, qB, z);
  STEP(pY0, sm.cy[1], qA, qB, w);
#undef STEP
#undef REFILL

  // s[b,h,127-w] = dot(v, z_w): 4 threads per w, 64 channels each
  {
    const int w    = tid >> 2;
    const int part = tid & 3;
    const _Float16* zr = sm.zh + w * 256 + part * 64;
    const float*    vr = conv1 + part * 64;
    float s = 0.f;
#pragma unroll
    for (int j = 0; j < 8; ++j) {
      f16x8 zv = *(const f16x8*)(zr + j * 8);
      float4 v0 = *(const float4*)(vr + j * 8);
      float4 v1 = *(const float4*)(vr + j * 8 + 4);
      s += v0.x * (float)zv[0] + v0.y * (float)zv[1]
         + v0.z * (float)zv[2] + v0.w * (float)zv[3]
         + v1.x * (float)zv[4] + v1.y * (float)zv[5]
         + v1.z * (float)zv[6] + v1.w * (float)zv[7];
    }
    s += __shfl_xor(s, 1, 64);
    s += __shfl_xor(s, 2, 64);
    if (part == 0) sout[(blockIdx.x << 7) + (127 - w)] = s;
  }
}

// ---- bilinear 4x upsample (align_corners) of s: (2,64,128) -> (2,256,512) --
static __device__ __forceinline__ float bilin(const float* __restrict__ s,
                                              int idx) {
  int bb  = idx >> 17;
  int rem = idx & 131071;
  int ho  = rem >> 9;
  int wo  = rem & 511;
  const float SY = 63.0f / 255.0f, SX = 127.0f / 511.0f;
  float fy = (float)ho * SY;
  int y0 = (int)fy; int y1 = min(y0 + 1, 63); float wy = fy - (float)y0;
  float fx = (float)wo * SX;
  int x0 = (int)fx; int x1 = min(x0 + 1, 127); float wx = fx - (float)x0;
  const float* sb = s + bb * 8192;
  float cA = sb[y0 * 128 + x0] * (1.f - wy) + sb[y1 * 128 + x0] * wy;
  float cB = sb[y0 * 128 + x1] * (1.f - wy) + sb[y1 * 128 + x1] * wy;
  return cA * (1.f - wx) + cB * wx;
}

// ---- kernel 2: global sum / sumsq of upsampled field -----------------------
extern "C" __global__ void k_stats(const float* __restrict__ s,
                                   float* __restrict__ stats) {
  int tid  = threadIdx.x;
  int base = blockIdx.x * 1024 + tid;
  float sum = 0.f, ssq = 0.f;
#pragma unroll
  for (int i = 0; i < 4; ++i) {
    float u = bilin(s, base + i * 256);
    sum += u; ssq += u * u;
  }
#pragma unroll
  for (int off = 32; off > 0; off >>= 1) {
    sum += __shfl_xor(sum, off, 64);
    ssq += __shfl_xor(ssq, off, 64);
  }
  __shared__ float ls[4], lq[4];
  int wv = tid >> 6;
  if ((tid & 63) == 0) { ls[wv] = sum; lq[wv] = ssq; }
  __syncthreads();
  if (tid == 0) {
    atomicAdd(&stats[0], ls[0] + ls[1] + ls[2] + ls[3]);
    atomicAdd(&stats[1], lq[0] + lq[1] + lq[2] + lq[3]);
  }
}

// ---- kernel 3: normalize + sigmoid -----------------------------------------
extern "C" __global__ void k_norm(const float* __restrict__ s,
                                  const float* __restrict__ stats,
                                  const float* __restrict__ gamma,
                                  const float* __restrict__ beta,
                                  float* __restrict__ out) {
  int tid  = threadIdx.x;
  int base = blockIdx.x * 1024 + tid;
  const float invN = 1.f / 262144.f;
  float mean  = stats[0] * invN;
  float var   = stats[1] * invN - mean * mean;
  float scale = rsqrtf(var + 1e-5f) * gamma[0];
  float bias  = beta[0] - mean * scale;
#pragma unroll
  for (int i = 0; i < 4; ++i) {
    int idx = base + i * 256;
    float u = bilin(s, idx);
    float x = u * scale + bias;
    out[idx] = 1.f / (1.f + __expf(-x));
  }
}

// ---------------------------------------------------------------------------
extern "C" void kernel_launch(void* const* d_in, const int* in_sizes, int n_in,
                              void* d_out, int out_size, void* d_ws, size_t ws_size,
                              hipStream_t stream) {
  const float* p2    = (const float*)d_in[0];   // (2,256,64,128)
  const float* convw = (const float*)d_in[1];   // (256,256,1,9)
  const float* conv1 = (const float*)d_in[2];   // (1,256,1,1)
  const float* gamma = (const float*)d_in[3];   // (1,)
  const float* beta  = (const float*)d_in[4];   // (1,)
  float* out = (float*)d_out;                   // (2,1,256,512) fp32

  char* ws = (char*)d_ws;
  float*    s     = (float*)ws;                 // 16384 floats  [0, 64KB)
  float*    stats = (float*)(ws + 65536);       // 2 floats
  _Float16* Md    = (_Float16*)(ws + 65792);    // 65536 f16 (128 KB)

  hipLaunchKernelGGL(k_extract, dim3(576), dim3(256), 0, stream, convw, Md);
  hipLaunchKernelGGL(k_scan,    dim3(128), dim3(512), 0, stream, p2, Md, conv1, s, stats);
  hipLaunchKernelGGL(k_stats,   dim3(256), dim3(256), 0, stream, s, stats);
  hipLaunchKernelGGL(k_norm,    dim3(256), dim3(256), 0, stream, s, stats, gamma, beta, out);
}